// Round 1
// baseline (2662.285 us; speedup 1.0000x reference)
//
#include <hip/hip_runtime.h>
#include <math.h>

#define B_     64
#define NPG_   4096
#define M_     8
#define DN_    512
#define DQ_    256
#define N_     (B_*NPG_)
#define KSEL_  1229          // ceil(0.3 * 4096)

#define BM 64
#define BK 16

// ---------------------------------------------------------------------------
// Kernel 1: scores[n][m] = sum_c gelu(x[n]·Wn[:,c] + bn[c]) * u[m][b(n)][c]
// 64 rows x 256 cols per block, BK=16, fp32 VALU GEMM, fused gelu+score.
// ---------------------------------------------------------------------------
__global__ __launch_bounds__(256) void k_score(
    const float* __restrict__ x, const float* __restrict__ u,
    const float* __restrict__ Wn, const float* __restrict__ bn,
    float* __restrict__ scores)
{
    // xs transposed [k][row], padded +4 so the 4-row float4 reads spread banks
    __shared__ __align__(16) float xs[BK][BM + 4];
    __shared__ __align__(16) float ws[BK][DQ_];
    __shared__ __align__(16) float us[M_][DQ_];
    __shared__ float bns[DQ_];

    const int tid  = threadIdx.x;
    const int row0 = blockIdx.x * BM;
    const int b    = row0 >> 12;          // row0 / NPG_

    // stage this graph's instruction vectors + bias (read in epilogue only;
    // loop barriers below cover the dependency)
    #pragma unroll
    for (int p = 0; p < 8; ++p) {
        int idx = p * 256 + tid;
        us[idx >> 8][idx & 255] = u[((idx >> 8) * B_ + b) * DQ_ + (idx & 255)];
    }
    bns[tid] = bn[tid];

    const int ty = tid >> 4;              // 0..15 : row group (4 rows)
    const int tx = tid & 15;              // 0..15 : col group

    float acc[4][16];
    #pragma unroll
    for (int i = 0; i < 4; ++i)
        #pragma unroll
        for (int j = 0; j < 16; ++j) acc[i][j] = 0.0f;

    const int xr = tid >> 2;              // staging row 0..63
    const int xk = (tid & 3) * 4;         // staging k offset 0..12
    const long xbase = (long)(row0 + xr) * DN_ + xk;

    // prologue: prefetch tile 0
    float4 xv = *(const float4*)(x + xbase);
    float4 wv[4];
    #pragma unroll
    for (int p = 0; p < 4; ++p) {
        int q = p * 256 + tid;
        wv[p] = *(const float4*)(Wn + (long)(q >> 6) * DQ_ + (q & 63) * 4);
    }

    for (int kt = 0; kt < DN_ / BK; ++kt) {
        __syncthreads();                  // previous tile fully consumed
        xs[xk + 0][xr] = xv.x;
        xs[xk + 1][xr] = xv.y;
        xs[xk + 2][xr] = xv.z;
        xs[xk + 3][xr] = xv.w;
        #pragma unroll
        for (int p = 0; p < 4; ++p) {
            int q = p * 256 + tid;
            *(float4*)&ws[q >> 6][(q & 63) * 4] = wv[p];
        }
        __syncthreads();

        if (kt + 1 < DN_ / BK) {          // prefetch next tile (latency hidden)
            int k0 = (kt + 1) * BK;
            xv = *(const float4*)(x + xbase + k0);
            #pragma unroll
            for (int p = 0; p < 4; ++p) {
                int q = p * 256 + tid;
                wv[p] = *(const float4*)(Wn + (long)(k0 + (q >> 6)) * DQ_ + (q & 63) * 4);
            }
        }

        #pragma unroll
        for (int k = 0; k < BK; ++k) {
            const float4 a = *(const float4*)&xs[k][ty * 4];
            #pragma unroll
            for (int j = 0; j < 4; ++j) {
                const float4 w = *(const float4*)&ws[k][j * 64 + tx * 4];
                acc[0][j*4+0] += a.x * w.x; acc[0][j*4+1] += a.x * w.y;
                acc[0][j*4+2] += a.x * w.z; acc[0][j*4+3] += a.x * w.w;
                acc[1][j*4+0] += a.y * w.x; acc[1][j*4+1] += a.y * w.y;
                acc[1][j*4+2] += a.y * w.z; acc[1][j*4+3] += a.y * w.w;
                acc[2][j*4+0] += a.z * w.x; acc[2][j*4+1] += a.z * w.y;
                acc[2][j*4+2] += a.z * w.z; acc[2][j*4+3] += a.z * w.w;
                acc[3][j*4+0] += a.w * w.x; acc[3][j*4+1] += a.w * w.y;
                acc[3][j*4+2] += a.w * w.z; acc[3][j*4+3] += a.w * w.w;
            }
        }
    }

    // epilogue: gelu + dot with the 8 instruction vectors, reduce over tx
    float part[4][8];
    #pragma unroll
    for (int i = 0; i < 4; ++i)
        #pragma unroll
        for (int m = 0; m < 8; ++m) part[i][m] = 0.0f;

    #pragma unroll
    for (int j = 0; j < 4; ++j) {
        #pragma unroll
        for (int r = 0; r < 4; ++r) {
            const int c = j * 64 + tx * 4 + r;
            const float bnc = bns[c];
            #pragma unroll
            for (int i = 0; i < 4; ++i) {
                const float z = acc[i][j * 4 + r] + bnc;
                const float h = 0.5f * z * (1.0f + erff(z * 0.7071067811865476f));
                #pragma unroll
                for (int m = 0; m < 8; ++m) part[i][m] += h * us[m][c];
            }
        }
    }

    #pragma unroll
    for (int mask = 1; mask < 16; mask <<= 1)
        #pragma unroll
        for (int i = 0; i < 4; ++i)
            #pragma unroll
            for (int m = 0; m < 8; ++m)
                part[i][m] += __shfl_xor(part[i][m], mask, 64);

    #pragma unroll
    for (int m = 0; m < 8; ++m)
        if (tx == m)
            #pragma unroll
            for (int i = 0; i < 4; ++i)
                scores[(long)(row0 + ty * 4 + i) * M_ + m] = part[i][m];
}

// ---------------------------------------------------------------------------
// Kernel 2: per-graph softmax-normalize -> gate -> exact top-K threshold
// (4-pass radix select on float bit patterns; gates are >= 0) -> binary mask.
// One block (256 threads) per graph.
// ---------------------------------------------------------------------------
__global__ __launch_bounds__(256) void k_mask(
    const float* __restrict__ scores, float* __restrict__ out)
{
    __shared__ float red[256];
    __shared__ float gateLDS[NPG_];
    __shared__ float gmaxS[M_];
    __shared__ float ginvS[M_];
    __shared__ unsigned hist[256];
    __shared__ unsigned sPrefix;
    __shared__ int sWant;

    const int b   = blockIdx.x;
    const int tid = threadIdx.x;
    const float* sb = scores + (long)b * NPG_ * M_;

    // pass A: per-m max over the graph's 4096 nodes
    float lmax[8];
    #pragma unroll
    for (int m = 0; m < 8; ++m) lmax[m] = -INFINITY;
    for (int it = 0; it < 16; ++it) {
        const int n = it * 256 + tid;
        const float4 s0 = *(const float4*)(sb + (long)n * 8);
        const float4 s1 = *(const float4*)(sb + (long)n * 8 + 4);
        lmax[0] = fmaxf(lmax[0], s0.x); lmax[1] = fmaxf(lmax[1], s0.y);
        lmax[2] = fmaxf(lmax[2], s0.z); lmax[3] = fmaxf(lmax[3], s0.w);
        lmax[4] = fmaxf(lmax[4], s1.x); lmax[5] = fmaxf(lmax[5], s1.y);
        lmax[6] = fmaxf(lmax[6], s1.z); lmax[7] = fmaxf(lmax[7], s1.w);
    }
    for (int m = 0; m < 8; ++m) {
        red[tid] = lmax[m]; __syncthreads();
        for (int s = 128; s > 0; s >>= 1) {
            if (tid < s) red[tid] = fmaxf(red[tid], red[tid + s]);
            __syncthreads();
        }
        if (tid == 0) gmaxS[m] = red[0];
        __syncthreads();
    }

    // pass B: per-m sum of exp(s - max)
    float lsum[8];
    #pragma unroll
    for (int m = 0; m < 8; ++m) lsum[m] = 0.0f;
    for (int it = 0; it < 16; ++it) {
        const int n = it * 256 + tid;
        const float4 s0 = *(const float4*)(sb + (long)n * 8);
        const float4 s1 = *(const float4*)(sb + (long)n * 8 + 4);
        lsum[0] += expf(s0.x - gmaxS[0]); lsum[1] += expf(s0.y - gmaxS[1]);
        lsum[2] += expf(s0.z - gmaxS[2]); lsum[3] += expf(s0.w - gmaxS[3]);
        lsum[4] += expf(s1.x - gmaxS[4]); lsum[5] += expf(s1.y - gmaxS[5]);
        lsum[6] += expf(s1.z - gmaxS[6]); lsum[7] += expf(s1.w - gmaxS[7]);
    }
    for (int m = 0; m < 8; ++m) {
        red[tid] = lsum[m]; __syncthreads();
        for (int s = 128; s > 0; s >>= 1) {
            if (tid < s) red[tid] += red[tid + s];
            __syncthreads();
        }
        if (tid == 0) ginvS[m] = 1.0f / red[0];
        __syncthreads();
    }

    // pass C: gate[n] = sum_m attn
    for (int it = 0; it < 16; ++it) {
        const int n = it * 256 + tid;
        const float4 s0 = *(const float4*)(sb + (long)n * 8);
        const float4 s1 = *(const float4*)(sb + (long)n * 8 + 4);
        float g = 0.0f;
        g += expf(s0.x - gmaxS[0]) * ginvS[0];
        g += expf(s0.y - gmaxS[1]) * ginvS[1];
        g += expf(s0.z - gmaxS[2]) * ginvS[2];
        g += expf(s0.w - gmaxS[3]) * ginvS[3];
        g += expf(s1.x - gmaxS[4]) * ginvS[4];
        g += expf(s1.y - gmaxS[5]) * ginvS[5];
        g += expf(s1.z - gmaxS[6]) * ginvS[6];
        g += expf(s1.w - gmaxS[7]) * ginvS[7];
        gateLDS[n] = g;
    }
    __syncthreads();

    // pass D: exact K-th largest via 4x8-bit radix select on float bits
    if (tid == 0) { sPrefix = 0u; sWant = KSEL_; }
    __syncthreads();
    const unsigned himask[4] = {0u, 0xFF000000u, 0xFFFF0000u, 0xFFFFFF00u};
    for (int r = 0; r < 4; ++r) {
        hist[tid] = 0u;
        __syncthreads();
        const unsigned pfx = sPrefix;
        const unsigned hm  = himask[r];
        const int shift = 24 - 8 * r;
        for (int it = 0; it < 16; ++it) {
            const unsigned uv = __float_as_uint(gateLDS[it * 256 + tid]);
            if ((uv & hm) == pfx)
                atomicAdd(&hist[(uv >> shift) & 255u], 1u);
        }
        __syncthreads();
        if (tid == 0) {
            int want = sWant;
            unsigned acc = 0u;
            for (int bb = 255; bb >= 0; --bb) {
                const unsigned h = hist[bb];
                if (acc + h >= (unsigned)want) {
                    sWant   = want - (int)acc;
                    sPrefix = pfx | ((unsigned)bb << shift);
                    break;
                }
                acc += h;
            }
        }
        __syncthreads();
    }
    const float kth = __uint_as_float(sPrefix);

    // pass E: mask = gate >= kth
    for (int it = 0; it < 16; ++it) {
        const int n = it * 256 + tid;
        out[(long)b * NPG_ + n] = (gateLDS[n] >= kth) ? 1.0f : 0.0f;
    }
}

extern "C" void kernel_launch(void* const* d_in, const int* in_sizes, int n_in,
                              void* d_out, int out_size, void* d_ws, size_t ws_size,
                              hipStream_t stream) {
    const float* x  = (const float*)d_in[0];
    const float* u  = (const float*)d_in[1];
    const float* Wn = (const float*)d_in[2];
    const float* bn = (const float*)d_in[3];
    // d_in[4] = batch (equal segments, implied by layout), d_in[5] = edge_index (unused)

    float* scores = (float*)d_ws;              // N_ * M_ floats = 8 MB
    float* out    = (float*)d_out;

    k_score<<<N_ / BM, 256, 0, stream>>>(x, u, Wn, bn, scores);
    k_mask<<<B_, 256, 0, stream>>>(scores, out);
}